// Round 5
// baseline (590.226 us; speedup 1.0000x reference)
//
#include <hip/hip_runtime.h>
#include <hip/hip_bf16.h>
#include <cstdint>
#include <cstddef>

// Problem constants
#define NB   64
#define NS   8
#define DIM  2048
#define FF   4096
#define NE   8
#define TOK  512            // NB*NS
#define NPAIR 1024          // TOK*2

// GEMM tiling
#define BM   256            // M capacity (max Me ~ 170 << 256; single pass)
#define BN   64             // N-cols per block
#define BK   32             // K per stage (one 16x16x32 MFMA K-slice)

typedef __attribute__((ext_vector_type(4))) float f32x4;
typedef __attribute__((ext_vector_type(8))) short bf16x8;
typedef __attribute__((ext_vector_type(4))) short bf16x4;

#define MFMA16(a, b, c) __builtin_amdgcn_mfma_f32_16x16x32_bf16((a), (b), (c), 0, 0, 0)

// raw barrier: drain LDS ops only (NOT vmcnt — keep global prefetches in flight)
#define BARSYNC do { asm volatile("s_waitcnt lgkmcnt(0)" ::: "memory"); \
                     asm volatile("s_barrier" ::: "memory");            \
                     __builtin_amdgcn_sched_barrier(0); } while (0)

// round-half-up fp32 -> bf16 (0.5 ulp, 2 VALU ops)
static __device__ __forceinline__ short f2bf(float f) {
    unsigned u = __builtin_bit_cast(unsigned, f);
    return (short)((u + 0x8000u) >> 16);
}

// ---------------------------------------------------------------------------
// Kernel 1: gating (logits -> top-2 -> softmax) + x -> bf16 preconvert.
// ---------------------------------------------------------------------------
__global__ void gate_topk(const float* __restrict__ x, const float* __restrict__ gw,
                          unsigned short* __restrict__ xbf,
                          int* __restrict__ tok_expert, float* __restrict__ tok_gatew) {
    int token = blockIdx.x;
    int lane  = threadIdx.x;
    const float* xr = x + (size_t)token * DIM;

    float acc[NE];
#pragma unroll
    for (int e = 0; e < NE; ++e) acc[e] = 0.f;

    for (int d0 = lane * 8; d0 < DIM; d0 += 64 * 8) {
        float4 xa = *(const float4*)(xr + d0);
        float4 xb = *(const float4*)(xr + d0 + 4);
        bf16x8 v;
        v[0] = f2bf(xa.x); v[1] = f2bf(xa.y); v[2] = f2bf(xa.z); v[3] = f2bf(xa.w);
        v[4] = f2bf(xb.x); v[5] = f2bf(xb.y); v[6] = f2bf(xb.z); v[7] = f2bf(xb.w);
        *(bf16x8*)(xbf + (size_t)token * DIM + d0) = v;
#pragma unroll
        for (int j = 0; j < 8; ++j) {
            float xv = (j < 4) ? ((const float*)&xa)[j] : ((const float*)&xb)[j - 4];
            const float4* g = (const float4*)(gw + (size_t)(d0 + j) * NE);
            float4 g0 = g[0], g1 = g[1];
            acc[0] += xv * g0.x; acc[1] += xv * g0.y;
            acc[2] += xv * g0.z; acc[3] += xv * g0.w;
            acc[4] += xv * g1.x; acc[5] += xv * g1.y;
            acc[6] += xv * g1.z; acc[7] += xv * g1.w;
        }
    }
#pragma unroll
    for (int off = 32; off >= 1; off >>= 1) {
#pragma unroll
        for (int e = 0; e < NE; ++e) acc[e] += __shfl_down(acc[e], off);
    }
    if (lane == 0) {
        float b1 = -1e30f, b2 = -1e30f; int i1 = 0, i2 = 0;
#pragma unroll
        for (int e = 0; e < NE; ++e) {
            float v = acc[e];
            if (v > b1) { b2 = b1; i2 = i1; b1 = v; i1 = e; }
            else if (v > b2) { b2 = v; i2 = e; }
        }
        float t = __expf(b2 - b1);
        tok_expert[token * 2 + 0] = i1;
        tok_expert[token * 2 + 1] = i2;
        tok_gatew[token * 2 + 0] = 1.f / (1.f + t);
        tok_gatew[token * 2 + 1] = t / (1.f + t);
    }
}

// ---------------------------------------------------------------------------
// Kernel 2: deterministic per-expert token lists (wave-per-expert ballot scan)
// ---------------------------------------------------------------------------
__global__ void build_lists(const int* __restrict__ tok_expert,
                            const float* __restrict__ tok_gatew,
                            int* __restrict__ counts, int* __restrict__ offsets,
                            int* __restrict__ row_token, float* __restrict__ row_gatew,
                            int* __restrict__ pair_row) {
    __shared__ int s_off[NE];
    __shared__ int s_cnt[NE];
    int e    = threadIdx.x >> 6;
    int lane = threadIdx.x & 63;
    unsigned long long lt = (1ull << lane) - 1ull;

    int cnt = 0;
    for (int base = 0; base < NPAIR; base += 64) {
        int id = tok_expert[base + lane];
        unsigned long long m = __ballot(id == e);
        cnt += __popcll(m);
    }
    if (lane == 0) s_cnt[e] = cnt;
    __syncthreads();
    if (threadIdx.x == 0) {
        int o = 0;
        for (int i = 0; i < NE; ++i) {
            int c = s_cnt[i];
            counts[i] = c; offsets[i] = o; s_off[i] = o; o += c;
        }
    }
    __syncthreads();

    int rbase = s_off[e];
    for (int base = 0; base < NPAIR; base += 64) {
        int entry = base + lane;
        int id = tok_expert[entry];
        bool match = (id == e);
        unsigned long long m = __ballot(match);
        int pre = __popcll(m & lt);
        if (match) {
            int row = rbase + pre;
            row_token[row] = entry >> 1;
            row_gatew[row] = tok_gatew[entry];
            pair_row[entry] = row;
        }
        rbase += __popcll(m);
    }
}

// ---------------------------------------------------------------------------
// Kernel 3: H = silu(Xbf*w1) .* (Xbf*w3).  grid = 8 x 64 f-tiles, 512 thr.
// A: direct per-lane bf16x8 gathers (L2-resident xbf), double-buffered in regs.
// B: each thread loads ONE frag-chunk (8 strided fp32, coalesced across wave),
//    cvt in regs, one ds_write_b128; frag read = one ds_read_b128.
// All loads compiler-visible -> precise auto-waitcnt; raw barrier keeps
// prefetches in flight (no vmcnt(0) drain).
// ---------------------------------------------------------------------------
#define F1BODY(P, AU, AL, BU, BL, IA, IB, WB, KT) do {                      \
    if (IA) { _Pragma("unroll")                                             \
        for (int f = 0; f < 4; ++f)                                         \
            AL[f] = *(const bf16x8*)(arow[f] + ((KT) + 1) * BK); }          \
    if (IB) { _Pragma("unroll")                                             \
        for (int j = 0; j < 8; ++j)                                         \
            BL[j] = bbase[((size_t)((KT) + 2) * BK + j) * FF]; }            \
    __builtin_amdgcn_sched_barrier(0);                                      \
    bf16x8 bf1[2], bf3[2];                                                  \
    _Pragma("unroll")                                                       \
    for (int nf = 0; nf < 2; ++nf) {                                        \
        int ch = (wn * 32 + nf * 16 + l15) + (lg << 6);                     \
        bf1[nf] = *(const bf16x8*)&Bs[P][0][ch * 8];                        \
        bf3[nf] = *(const bf16x8*)&Bs[P][1][ch * 8];                        \
    }                                                                       \
    _Pragma("unroll")                                                       \
    for (int f = 0; f < 4; ++f) {                                           \
        _Pragma("unroll")                                                   \
        for (int nf = 0; nf < 2; ++nf) {                                    \
            acc1[f][nf] = MFMA16(AU[f], bf1[nf], acc1[f][nf]);              \
            acc3[f][nf] = MFMA16(AU[f], bf3[nf], acc3[f][nf]);              \
        }                                                                   \
    }                                                                       \
    if (WB) {                                                               \
        bf16x8 wv;                                                          \
        _Pragma("unroll")                                                   \
        for (int j = 0; j < 8; ++j) wv[j] = f2bf(BU[j]);                    \
        *(bf16x8*)&Bs[(P) ^ 1][bmat][bchunk * 8] = wv;                      \
    }                                                                       \
    BARSYNC;                                                                \
} while (0)

__global__ __launch_bounds__(512, 4) void ffn1(
    const unsigned short* __restrict__ xbf, const float* __restrict__ w1,
    const float* __restrict__ w3,
    const int* __restrict__ counts, const int* __restrict__ offsets,
    const int* __restrict__ row_token, unsigned short* __restrict__ Hbuf) {
    __shared__ __align__(16) unsigned short Bs[2][2][2048];   // 16 KB

    int bid = blockIdx.x;
    int e  = bid >> 6;
    int f0 = (bid & 63) * BN;

    int Me = counts[e];
    if (Me == 0) return;
    int off = offsets[e];

    int t = threadIdx.x;
    int lane = t & 63;
    int w = t >> 6;
    int wm = w >> 1, wn = w & 1;                 // 4 M-waves x 2 N-waves
    int l15 = lane & 15, lg = lane >> 4;

    const float* w1e = w1 + (size_t)e * DIM * FF + f0;
    const float* w3e = w3 + (size_t)e * DIM * FF + f0;

    // B staging role: thread t owns frag chunk (bcol, blg) of mat bmat
    int bmat = t >> 8;                 // 0: w1, 1: w3 (uniform per wave)
    int bchunk = t & 255;
    int bcol = bchunk & 63, blg = bchunk >> 6;
    const float* bbase = (bmat ? w3e : w1e) + (size_t)(blg * 8) * FF + bcol;

    const int NSTG = DIM / BK;                   // 64

    for (int mb = 0; mb < Me; mb += BM) {
        // A row pointers (per-lane; lg*8 k-offset folded in)
        const unsigned short* arow[4];
#pragma unroll
        for (int f = 0; f < 4; ++f) {
            int rl = mb + wm * 64 + f * 16 + l15;
            int rr = (rl < Me) ? rl : (Me - 1);
            arow[f] = xbf + (size_t)row_token[off + rr] * DIM + lg * 8;
        }

        f32x4 acc1[4][2], acc3[4][2];
#pragma unroll
        for (int f = 0; f < 4; ++f)
#pragma unroll
            for (int nf = 0; nf < 2; ++nf) {
                acc1[f][nf] = (f32x4){0.f, 0.f, 0.f, 0.f};
                acc3[f][nf] = (f32x4){0.f, 0.f, 0.f, 0.f};
            }

        // prologue: B(0) -> regs -> LDS buf0; A(0), B(1) in flight
        float bP[8], bC[8], bN[8];
        bf16x8 aC[4], aN[4];
#pragma unroll
        for (int j = 0; j < 8; ++j) bP[j] = bbase[(size_t)j * FF];
#pragma unroll
        for (int f = 0; f < 4; ++f) aC[f] = *(const bf16x8*)(arow[f]);
#pragma unroll
        for (int j = 0; j < 8; ++j) bC[j] = bbase[((size_t)BK + j) * FF];
        {
            bf16x8 wv;
#pragma unroll
            for (int j = 0; j < 8; ++j) wv[j] = f2bf(bP[j]);
            *(bf16x8*)&Bs[0][bmat][bchunk * 8] = wv;
        }
        BARSYNC;

        for (int s = 0; s < NSTG - 2; s += 2) {
            F1BODY(0, aC, aN, bC, bN, true, true, true, s);
            F1BODY(1, aN, aC, bN, bC, true, true, true, s + 1);
        }
        F1BODY(0, aC, aN, bC, bN, true, false, true, NSTG - 2);
        F1BODY(1, aN, aC, bN, bC, false, false, false, NSTG - 1);

        // epilogue: silu(a1)*a3 -> bf16 H
#pragma unroll
        for (int f = 0; f < 4; ++f)
#pragma unroll
            for (int nf = 0; nf < 2; ++nf)
#pragma unroll
                for (int r = 0; r < 4; ++r) {
                    int rl = mb + wm * 64 + f * 16 + lg * 4 + r;
                    if (rl < Me) {
                        float a1 = acc1[f][nf][r], a3 = acc3[f][nf][r];
                        float h = (a1 / (1.f + __expf(-a1))) * a3;
                        Hbuf[(size_t)(off + rl) * FF + f0 + wn * 32 + nf * 16 + l15] =
                            (unsigned short)f2bf(h);
                    }
                }
    }
}

// ---------------------------------------------------------------------------
// Kernel 4: OutPair = (H @ w2) * gate_weight.  grid = 8 x 32 d-tiles, 512 thr.
// Same structure; B staging split in half-chunks (4 fp32 loads + b64 write).
// ---------------------------------------------------------------------------
#define F2BODY(P, AU, AL, BU, BL, IA, IB, WB, KT) do {                      \
    if (IA) { _Pragma("unroll")                                             \
        for (int f = 0; f < 4; ++f)                                         \
            AL[f] = *(const bf16x8*)(arow[f] + ((KT) + 1) * BK); }          \
    if (IB) { _Pragma("unroll")                                             \
        for (int j = 0; j < 4; ++j)                                         \
            BL[j] = bbase[((size_t)((KT) + 2) * BK + j) * DIM]; }           \
    __builtin_amdgcn_sched_barrier(0);                                      \
    bf16x8 bfw[2];                                                          \
    _Pragma("unroll")                                                       \
    for (int nf = 0; nf < 2; ++nf) {                                        \
        int ch = (wn * 32 + nf * 16 + l15) + (lg << 6);                     \
        bfw[nf] = *(const bf16x8*)&Bs[P][ch * 8];                           \
    }                                                                       \
    _Pragma("unroll")                                                       \
    for (int f = 0; f < 4; ++f) {                                           \
        _Pragma("unroll")                                                   \
        for (int nf = 0; nf < 2; ++nf)                                      \
            acc[f][nf] = MFMA16(AU[f], bfw[nf], acc[f][nf]);                \
    }                                                                       \
    if (WB) {                                                               \
        bf16x4 wv;                                                          \
        _Pragma("unroll")                                                   \
        for (int j = 0; j < 4; ++j) wv[j] = f2bf(BU[j]);                    \
        *(bf16x4*)&Bs[(P) ^ 1][bchunk * 8 + bhalf * 4] = wv;                \
    }                                                                       \
    BARSYNC;                                                                \
} while (0)

__global__ __launch_bounds__(512, 4) void ffn2(
    const unsigned short* __restrict__ Hbuf, const float* __restrict__ w2,
    const int* __restrict__ counts, const int* __restrict__ offsets,
    const float* __restrict__ row_gatew, float* __restrict__ OP) {
    __shared__ __align__(16) unsigned short Bs[2][2048];      // 8 KB

    int bid = blockIdx.x;
    int e  = bid >> 5;
    int d0 = (bid & 31) * BN;

    int Me = counts[e];
    if (Me == 0) return;
    int off = offsets[e];

    int t = threadIdx.x;
    int lane = t & 63;
    int w = t >> 6;
    int wm = w >> 1, wn = w & 1;
    int l15 = lane & 15, lg = lane >> 4;

    const float* w2e = w2 + (size_t)e * FF * DIM + d0;

    // B staging: thread t owns HALF of frag chunk (bcol, blg): 4 k-values
    int bchunk = t & 255;
    int bhalf  = t >> 8;               // 0 or 1 (uniform per wave)
    int bcol = bchunk & 63, blg = bchunk >> 6;
    const float* bbase = w2e + (size_t)(blg * 8 + bhalf * 4) * DIM + bcol;

    const int NSTG = FF / BK;                    // 128

    for (int mb = 0; mb < Me; mb += BM) {
        const unsigned short* arow[4];
#pragma unroll
        for (int f = 0; f < 4; ++f) {
            int rl = mb + wm * 64 + f * 16 + l15;
            int rr = (rl < Me) ? rl : (Me - 1);
            arow[f] = Hbuf + (size_t)(off + rr) * FF + lg * 8;
        }

        f32x4 acc[4][2];
#pragma unroll
        for (int f = 0; f < 4; ++f)
#pragma unroll
            for (int nf = 0; nf < 2; ++nf) acc[f][nf] = (f32x4){0.f, 0.f, 0.f, 0.f};

        float bP[4], bC[4], bN[4];
        bf16x8 aC[4], aN[4];
#pragma unroll
        for (int j = 0; j < 4; ++j) bP[j] = bbase[(size_t)j * DIM];
#pragma unroll
        for (int f = 0; f < 4; ++f) aC[f] = *(const bf16x8*)(arow[f]);
#pragma unroll
        for (int j = 0; j < 4; ++j) bC[j] = bbase[((size_t)BK + j) * DIM];
        {
            bf16x4 wv;
#pragma unroll
            for (int j = 0; j < 4; ++j) wv[j] = f2bf(bP[j]);
            *(bf16x4*)&Bs[0][bchunk * 8 + bhalf * 4] = wv;
        }
        BARSYNC;

        for (int s = 0; s < NSTG - 2; s += 2) {
            F2BODY(0, aC, aN, bC, bN, true, true, true, s);
            F2BODY(1, aN, aC, bN, bC, true, true, true, s + 1);
        }
        F2BODY(0, aC, aN, bC, bN, true, false, true, NSTG - 2);
        F2BODY(1, aN, aC, bN, bC, false, false, false, NSTG - 1);

#pragma unroll
        for (int f = 0; f < 4; ++f)
#pragma unroll
            for (int nf = 0; nf < 2; ++nf)
#pragma unroll
                for (int r = 0; r < 4; ++r) {
                    int rl = mb + wm * 64 + f * 16 + lg * 4 + r;
                    if (rl < Me) {
                        int grow = off + rl;
                        float g = row_gatew[grow];
                        OP[(size_t)grow * DIM + d0 + wn * 32 + nf * 16 + l15] =
                            acc[f][nf][r] * g;
                    }
                }
    }
}

// ---------------------------------------------------------------------------
// Kernel 5: out[token] = OP[pair0] + OP[pair1]
// ---------------------------------------------------------------------------
__global__ void combine(const float* __restrict__ OP, const int* __restrict__ pair_row,
                        float* __restrict__ out) {
    int idx = blockIdx.x * blockDim.x + threadIdx.x;
    int token = idx >> 9;
    int q = idx & 511;
    int r0 = pair_row[token * 2 + 0];
    int r1 = pair_row[token * 2 + 1];
    float4 a = *(const float4*)(OP + (size_t)r0 * DIM + q * 4);
    float4 b = *(const float4*)(OP + (size_t)r1 * DIM + q * 4);
    float4 o;
    o.x = a.x + b.x; o.y = a.y + b.y; o.z = a.z + b.z; o.w = a.w + b.w;
    *(float4*)(out + (size_t)token * DIM + q * 4) = o;
}

// ---------------------------------------------------------------------------
extern "C" void kernel_launch(void* const* d_in, const int* in_sizes, int n_in,
                              void* d_out, int out_size, void* d_ws, size_t ws_size,
                              hipStream_t stream) {
    const float* x  = (const float*)d_in[0];
    const float* gw = (const float*)d_in[1];
    const float* w1 = (const float*)d_in[2];
    const float* w3 = (const float*)d_in[3];
    const float* w2 = (const float*)d_in[4];
    float* out = (float*)d_out;

    char* ws = (char*)d_ws;
    unsigned short* Hbuf = (unsigned short*)ws;                 // 8 MB bf16 [1024][4096]
    float* OP            = (float*)(ws + 8388608);              // 8 MB f32  [1024][2048]
    unsigned short* xbf  = (unsigned short*)(ws + 16777216);    // 2 MB bf16 [512][2048]
    char* meta           = ws + 18874368;
    int*   tok_expert = (int*)(meta);
    float* tok_gatew  = (float*)(meta + 4096);
    int*   counts     = (int*)(meta + 8192);
    int*   offsets    = (int*)(meta + 8224);
    int*   row_token  = (int*)(meta + 8256);
    float* row_gatew  = (float*)(meta + 12352);
    int*   pair_row   = (int*)(meta + 16448);

    gate_topk<<<TOK, 64, 0, stream>>>(x, gw, xbf, tok_expert, tok_gatew);
    build_lists<<<1, 512, 0, stream>>>(tok_expert, tok_gatew, counts, offsets,
                                       row_token, row_gatew, pair_row);
    ffn1<<<NE * 64, 512, 0, stream>>>(xbf, w1, w3, counts, offsets, row_token, Hbuf);
    ffn2<<<NE * 32, 512, 0, stream>>>(Hbuf, w2, counts, offsets, row_gatew, OP);
    combine<<<1024, 256, 0, stream>>>(OP, pair_row, out);
}

// Round 6
// 236.573 us; speedup vs baseline: 2.4949x; 2.4949x over previous
//
#include <hip/hip_runtime.h>
#include <hip/hip_bf16.h>
#include <cstdint>
#include <cstddef>

// Problem constants
#define NB   64
#define NS   8
#define DIM  2048
#define FF   4096
#define NE   8
#define TOK  512            // NB*NS
#define NPAIR 1024          // TOK*2

// GEMM tiling
#define BM   192            // M capacity per pass (Binomial(512,1/4): mean 128, +6.5 sigma)
#define BN   64             // N-cols per block
#define BK   32             // K per stage (one 16x16x32 MFMA K-slice)

typedef __attribute__((ext_vector_type(4))) float f32x4;
typedef __attribute__((ext_vector_type(8))) short bf16x8;
typedef __attribute__((ext_vector_type(4))) short bf16x4;

#define MFMA16(a, b, c) __builtin_amdgcn_mfma_f32_16x16x32_bf16((a), (b), (c), 0, 0, 0)

#define VMCNT8  asm volatile("s_waitcnt vmcnt(8)" ::: "memory")
#define VMCNT4  asm volatile("s_waitcnt vmcnt(4)" ::: "memory")
#define VMCNT0  asm volatile("s_waitcnt vmcnt(0)" ::: "memory")
#define LGKMBAR do { asm volatile("s_waitcnt lgkmcnt(0)" ::: "memory"); \
                     asm volatile("s_barrier" ::: "memory");            \
                     __builtin_amdgcn_sched_barrier(0); } while (0)
#define SCHEDBAR __builtin_amdgcn_sched_barrier(0)

// round-half-up fp32 -> bf16 (0.5 ulp, 2 VALU ops)
static __device__ __forceinline__ short f2bf(float f) {
    unsigned u = __builtin_bit_cast(unsigned, f);
    return (short)((u + 0x8000u) >> 16);
}

// async global->LDS DMA, 16 bytes/lane; LDS dest must be wave-linear (base+lane*16),
// global source may be per-lane arbitrary.
static __device__ __forceinline__ void async16(void* l, const void* g) {
    __builtin_amdgcn_global_load_lds(
        (const __attribute__((address_space(1))) void*)g,
        (__attribute__((address_space(3))) void*)l, 16, 0, 0);
}

// ---------------------------------------------------------------------------
// Kernel 1: gating (logits -> top-2 -> softmax) + x -> bf16 preconvert.
// ---------------------------------------------------------------------------
__global__ void gate_topk(const float* __restrict__ x, const float* __restrict__ gw,
                          unsigned short* __restrict__ xbf,
                          int* __restrict__ tok_expert, float* __restrict__ tok_gatew) {
    int token = blockIdx.x;
    int lane  = threadIdx.x;
    const float* xr = x + (size_t)token * DIM;

    float acc[NE];
#pragma unroll
    for (int e = 0; e < NE; ++e) acc[e] = 0.f;

    for (int d0 = lane * 8; d0 < DIM; d0 += 64 * 8) {
        float4 xa = *(const float4*)(xr + d0);
        float4 xb = *(const float4*)(xr + d0 + 4);
        bf16x8 v;
        v[0] = f2bf(xa.x); v[1] = f2bf(xa.y); v[2] = f2bf(xa.z); v[3] = f2bf(xa.w);
        v[4] = f2bf(xb.x); v[5] = f2bf(xb.y); v[6] = f2bf(xb.z); v[7] = f2bf(xb.w);
        *(bf16x8*)(xbf + (size_t)token * DIM + d0) = v;
#pragma unroll
        for (int j = 0; j < 8; ++j) {
            float xv = (j < 4) ? ((const float*)&xa)[j] : ((const float*)&xb)[j - 4];
            const float4* g = (const float4*)(gw + (size_t)(d0 + j) * NE);
            float4 g0 = g[0], g1 = g[1];
            acc[0] += xv * g0.x; acc[1] += xv * g0.y;
            acc[2] += xv * g0.z; acc[3] += xv * g0.w;
            acc[4] += xv * g1.x; acc[5] += xv * g1.y;
            acc[6] += xv * g1.z; acc[7] += xv * g1.w;
        }
    }
#pragma unroll
    for (int off = 32; off >= 1; off >>= 1) {
#pragma unroll
        for (int e = 0; e < NE; ++e) acc[e] += __shfl_down(acc[e], off);
    }
    if (lane == 0) {
        float b1 = -1e30f, b2 = -1e30f; int i1 = 0, i2 = 0;
#pragma unroll
        for (int e = 0; e < NE; ++e) {
            float v = acc[e];
            if (v > b1) { b2 = b1; i2 = i1; b1 = v; i1 = e; }
            else if (v > b2) { b2 = v; i2 = e; }
        }
        float t = __expf(b2 - b1);
        tok_expert[token * 2 + 0] = i1;
        tok_expert[token * 2 + 1] = i2;
        tok_gatew[token * 2 + 0] = 1.f / (1.f + t);
        tok_gatew[token * 2 + 1] = t / (1.f + t);
    }
}

// ---------------------------------------------------------------------------
// Kernel 2: deterministic per-expert token lists (wave-per-expert ballot scan)
// ---------------------------------------------------------------------------
__global__ void build_lists(const int* __restrict__ tok_expert,
                            const float* __restrict__ tok_gatew,
                            int* __restrict__ counts, int* __restrict__ offsets,
                            int* __restrict__ row_token, float* __restrict__ row_gatew,
                            int* __restrict__ pair_row) {
    __shared__ int s_off[NE];
    __shared__ int s_cnt[NE];
    int e    = threadIdx.x >> 6;
    int lane = threadIdx.x & 63;
    unsigned long long lt = (1ull << lane) - 1ull;

    int cnt = 0;
    for (int base = 0; base < NPAIR; base += 64) {
        int id = tok_expert[base + lane];
        unsigned long long m = __ballot(id == e);
        cnt += __popcll(m);
    }
    if (lane == 0) s_cnt[e] = cnt;
    __syncthreads();
    if (threadIdx.x == 0) {
        int o = 0;
        for (int i = 0; i < NE; ++i) {
            int c = s_cnt[i];
            counts[i] = c; offsets[i] = o; s_off[i] = o; o += c;
        }
    }
    __syncthreads();

    int rbase = s_off[e];
    for (int base = 0; base < NPAIR; base += 64) {
        int entry = base + lane;
        int id = tok_expert[entry];
        bool match = (id == e);
        unsigned long long m = __ballot(match);
        int pre = __popcll(m & lt);
        if (match) {
            int row = rbase + pre;
            row_token[row] = entry >> 1;
            row_gatew[row] = tok_gatew[entry];
            pair_row[entry] = row;
        }
        rbase += __popcll(m);
    }
}

// ---------------------------------------------------------------------------
// Kernel 3: H = silu(Xbf*w1) .* (Xbf*w3).  grid = 8 x 64 f-tiles, 512 thr
// (8 waves, 4M x 2N).  A: global_load_lds DMA (bf16, chunk-XOR via source),
// double-buffered.  B: reg-stage (8 fp32/thread, coalesced) -> cvt -> packed
// bf16 frag-major LDS, double-buffered with X/Y regsets loaded 2 epochs ahead.
// Per epoch: DMA(s+1) | B-loads(s+2) | frag reads + 12 MFMA | write B(s+1) |
// vmcnt(8) (keeps B-loads in flight) | lgkm(0)+barrier.
// ---------------------------------------------------------------------------
#define EPOCH1(P, W, L, S, IA, IB) do {                                       \
    if (IA) stageA((P) ^ 1, ((S) + 1) * BK);                                  \
    SCHEDBAR;                                                                 \
    if (IB) {                                                                 \
        _Pragma("unroll")                                                     \
        for (int j = 0; j < 8; ++j)                                           \
            L[j] = bbase[((size_t)((S) + 2) * BK + j) * FF];                  \
    }                                                                         \
    bf16x8 a_[3];                                                             \
    _Pragma("unroll")                                                         \
    for (int f = 0; f < 3; ++f) {                                             \
        int m_ = wm * 48 + f * 16 + l15;                                      \
        a_[f] = *(const bf16x8*)&As[P][(size_t)m_ * BK + ((lg ^ (m_ & 3)) << 3)]; \
    }                                                                         \
    _Pragma("unroll")                                                         \
    for (int nf = 0; nf < 2; ++nf) {                                          \
        int ch_ = (wn * 32 + nf * 16 + l15) + (lg << 6);                      \
        bf16x8 b1_ = *(const bf16x8*)&Bs[P][0][ch_ * 8];                      \
        bf16x8 b3_ = *(const bf16x8*)&Bs[P][1][ch_ * 8];                      \
        _Pragma("unroll")                                                     \
        for (int f = 0; f < 3; ++f) {                                         \
            acc1[f][nf] = MFMA16(a_[f], b1_, acc1[f][nf]);                    \
            acc3[f][nf] = MFMA16(a_[f], b3_, acc3[f][nf]);                    \
        }                                                                     \
    }                                                                         \
    if (IA) {                                                                 \
        bf16x8 wv_;                                                           \
        _Pragma("unroll")                                                     \
        for (int j = 0; j < 8; ++j) wv_[j] = f2bf(W[j]);                      \
        *(bf16x8*)&Bs[(P) ^ 1][bmat][bchunk * 8] = wv_;                       \
    }                                                                         \
    if (IB) { VMCNT8; } else if (IA) { VMCNT0; }                              \
    LGKMBAR;                                                                  \
} while (0)

__global__ __launch_bounds__(512, 4) void ffn1(
    const unsigned short* __restrict__ xbf, const float* __restrict__ w1,
    const float* __restrict__ w3,
    const int* __restrict__ counts, const int* __restrict__ offsets,
    const int* __restrict__ row_token, unsigned short* __restrict__ Hbuf) {
    __shared__ __align__(16) unsigned short As[2][BM * BK];   // 24 KB
    __shared__ __align__(16) unsigned short Bs[2][2][2048];   // 16 KB

    int bid = blockIdx.x;
    int e  = bid >> 6;
    int f0 = (bid & 63) * BN;

    int Me = counts[e];
    if (Me == 0) return;
    int off = offsets[e];

    int t = threadIdx.x;
    int lane = t & 63;
    int w = t >> 6;
    int wm = w >> 1, wn = w & 1;                 // 4 M-waves x 2 N-waves
    int l15 = lane & 15, lg = lane >> 4;

    const float* w1e = w1 + (size_t)e * DIM * FF + f0;
    const float* w3e = w3 + (size_t)e * DIM * FF + f0;

    // B staging role: thread owns frag chunk (bcol, blg) of mat bmat
    int bmat = t >> 8;                 // 0: w1, 1: w3
    int bchunk = t & 255;
    int bcol = bchunk & 63, blg = bchunk >> 6;   // blg in [0,4)
    const float* bbase = (bmat ? w3e : w1e) + (size_t)(blg * 8) * FF + bcol;

    const int NSTG = DIM / BK;                   // 64

    for (int mb = 0; mb < Me; mb += BM) {
        // A staging sources (R3 scheme): chunk i -> (m=i>>2, c=i&3), source
        // chunk c^(m&3), LDS linear dest (XOR realized via source address)
        const unsigned short* asrc0;
        const unsigned short* asrc1;
        {
            int m0 = t >> 2, c0 = t & 3;
            int rl0 = mb + m0;
            int tok0 = row_token[off + ((rl0 < Me) ? rl0 : (Me - 1))];
            asrc0 = xbf + (size_t)tok0 * DIM + ((c0 ^ (m0 & 3)) << 3);
            int i1 = 512 + t;
            int m1 = i1 >> 2, c1 = i1 & 3;
            int rl1 = mb + m1;
            int tok1 = row_token[off + ((rl1 < Me) ? rl1 : (Me - 1))];
            asrc1 = xbf + (size_t)tok1 * DIM + ((c1 ^ (m1 & 3)) << 3);
        }

        f32x4 acc1[3][2], acc3[3][2];
#pragma unroll
        for (int f = 0; f < 3; ++f)
#pragma unroll
            for (int nf = 0; nf < 2; ++nf) {
                acc1[f][nf] = (f32x4){0.f, 0.f, 0.f, 0.f};
                acc3[f][nf] = (f32x4){0.f, 0.f, 0.f, 0.f};
            }

        auto stageA = [&](int buf, int k0) {
            async16(&As[buf][(size_t)t * 8], asrc0 + k0);
            if (t < 256) async16(&As[buf][(size_t)(512 + t) * 8], asrc1 + k0);
        };

        // prologue: DMA A(0); load B(0)->X, B(1)->Y; write X -> Bs[0]
        float bX[8], bY[8];
        stageA(0, 0);
        SCHEDBAR;
#pragma unroll
        for (int j = 0; j < 8; ++j) bX[j] = bbase[(size_t)j * FF];
#pragma unroll
        for (int j = 0; j < 8; ++j) bY[j] = bbase[((size_t)BK + j) * FF];
        {
            bf16x8 wv;
#pragma unroll
            for (int j = 0; j < 8; ++j) wv[j] = f2bf(bX[j]);
            *(bf16x8*)&Bs[0][bmat][bchunk * 8] = wv;
        }
        VMCNT8;            // A-DMA(0)+X retired; Y still in flight
        LGKMBAR;

        for (int s = 0; s < NSTG - 2; s += 2) {
            EPOCH1(0, bY, bX, s, 1, 1);
            EPOCH1(1, bX, bY, s + 1, 1, 1);
        }
        EPOCH1(0, bY, bX, NSTG - 2, 1, 0);
        EPOCH1(1, bX, bY, NSTG - 1, 0, 0);

        // epilogue: silu(a1)*a3 -> bf16 H
#pragma unroll
        for (int f = 0; f < 3; ++f)
#pragma unroll
            for (int nf = 0; nf < 2; ++nf)
#pragma unroll
                for (int r = 0; r < 4; ++r) {
                    int rl = mb + wm * 48 + f * 16 + lg * 4 + r;
                    if (rl < Me) {
                        float a1 = acc1[f][nf][r], a3 = acc3[f][nf][r];
                        float h = (a1 / (1.f + __expf(-a1))) * a3;
                        Hbuf[(size_t)(off + rl) * FF + f0 + wn * 32 + nf * 16 + l15] =
                            (unsigned short)f2bf(h);
                    }
                }
    }
}

// ---------------------------------------------------------------------------
// Kernel 4: OutPair = (H @ w2) * gate_weight.  grid = 8 x 32 d-tiles, 512 thr.
// Same pipeline; each thread owns a HALF frag chunk (4 fp32 / epoch).
// ---------------------------------------------------------------------------
#define EPOCH2(P, W, L, S, IA, IB) do {                                       \
    if (IA) stageA((P) ^ 1, ((S) + 1) * BK);                                  \
    SCHEDBAR;                                                                 \
    if (IB) {                                                                 \
        _Pragma("unroll")                                                     \
        for (int j = 0; j < 4; ++j)                                           \
            L[j] = bbase[((size_t)((S) + 2) * BK + j) * DIM];                 \
    }                                                                         \
    bf16x8 a_[3];                                                             \
    _Pragma("unroll")                                                         \
    for (int f = 0; f < 3; ++f) {                                             \
        int m_ = wm * 48 + f * 16 + l15;                                      \
        a_[f] = *(const bf16x8*)&As[P][(size_t)m_ * BK + ((lg ^ (m_ & 3)) << 3)]; \
    }                                                                         \
    _Pragma("unroll")                                                         \
    for (int nf = 0; nf < 2; ++nf) {                                          \
        int ch_ = (wn * 32 + nf * 16 + l15) + (lg << 6);                      \
        bf16x8 bw_ = *(const bf16x8*)&Bs[P][ch_ * 8];                         \
        _Pragma("unroll")                                                     \
        for (int f = 0; f < 3; ++f)                                           \
            acc[f][nf] = MFMA16(a_[f], bw_, acc[f][nf]);                      \
    }                                                                         \
    if (IA) {                                                                 \
        bf16x4 wv_;                                                           \
        _Pragma("unroll")                                                     \
        for (int j = 0; j < 4; ++j) wv_[j] = f2bf(W[j]);                      \
        *(bf16x4*)&Bs[(P) ^ 1][bchunk * 8 + bhalf * 4] = wv_;                 \
    }                                                                         \
    if (IB) { VMCNT4; } else if (IA) { VMCNT0; }                              \
    LGKMBAR;                                                                  \
} while (0)

__global__ __launch_bounds__(512, 4) void ffn2(
    const unsigned short* __restrict__ Hbuf, const float* __restrict__ w2,
    const int* __restrict__ counts, const int* __restrict__ offsets,
    const float* __restrict__ row_gatew, float* __restrict__ OP) {
    __shared__ __align__(16) unsigned short As[2][BM * BK];   // 24 KB
    __shared__ __align__(16) unsigned short Bs[2][2048];      //  8 KB

    int bid = blockIdx.x;
    int e  = bid >> 5;
    int d0 = (bid & 31) * BN;

    int Me = counts[e];
    if (Me == 0) return;
    int off = offsets[e];

    int t = threadIdx.x;
    int lane = t & 63;
    int w = t >> 6;
    int wm = w >> 1, wn = w & 1;
    int l15 = lane & 15, lg = lane >> 4;

    const float* w2e = w2 + (size_t)e * FF * DIM + d0;

    // B staging: thread owns half of frag chunk (bcol, blg): 4 k-values
    int bchunk = t & 255;
    int bhalf  = t >> 8;
    int bcol = bchunk & 63, blg = bchunk >> 6;
    const float* bbase = w2e + (size_t)(blg * 8 + bhalf * 4) * DIM + bcol;

    const int NSTG = FF / BK;                    // 128

    for (int mb = 0; mb < Me; mb += BM) {
        const unsigned short* asrc0;
        const unsigned short* asrc1;
        {
            int m0 = t >> 2, c0 = t & 3;
            int rl0 = mb + m0;
            asrc0 = Hbuf + (size_t)(off + ((rl0 < Me) ? rl0 : (Me - 1))) * FF
                         + ((c0 ^ (m0 & 3)) << 3);
            int i1 = 512 + t;
            int m1 = i1 >> 2, c1 = i1 & 3;
            int rl1 = mb + m1;
            asrc1 = Hbuf + (size_t)(off + ((rl1 < Me) ? rl1 : (Me - 1))) * FF
                         + ((c1 ^ (m1 & 3)) << 3);
        }

        f32x4 acc[3][2];
#pragma unroll
        for (int f = 0; f < 3; ++f)
#pragma unroll
            for (int nf = 0; nf < 2; ++nf) acc[f][nf] = (f32x4){0.f, 0.f, 0.f, 0.f};

        auto stageA = [&](int buf, int k0) {
            async16(&As[buf][(size_t)t * 8], asrc0 + k0);
            if (t < 256) async16(&As[buf][(size_t)(512 + t) * 8], asrc1 + k0);
        };

        float bX[4], bY[4];
        stageA(0, 0);
        SCHEDBAR;
#pragma unroll
        for (int j = 0; j < 4; ++j) bX[j] = bbase[(size_t)j * DIM];
#pragma unroll
        for (int j = 0; j < 4; ++j) bY[j] = bbase[((size_t)BK + j) * DIM];
        {
            bf16x4 wv;
#pragma unroll
            for (int j = 0; j < 4; ++j) wv[j] = f2bf(bX[j]);
            *(bf16x4*)&Bs[0][bchunk * 8 + bhalf * 4] = wv;
        }
        VMCNT4;
        LGKMBAR;

        for (int s = 0; s < NSTG - 2; s += 2) {
            EPOCH2(0, bY, bX, s, 1, 1);
            EPOCH2(1, bX, bY, s + 1, 1, 1);
        }
        EPOCH2(0, bY, bX, NSTG - 2, 1, 0);
        EPOCH2(1, bX, bY, NSTG - 1, 0, 0);

#pragma unroll
        for (int f = 0; f < 3; ++f)
#pragma unroll
            for (int nf = 0; nf < 2; ++nf)
#pragma unroll
                for (int r = 0; r < 4; ++r) {
                    int rl = mb + wm * 48 + f * 16 + lg * 4 + r;
                    if (rl < Me) {
                        int grow = off + rl;
                        float g = row_gatew[grow];
                        OP[(size_t)grow * DIM + d0 + wn * 32 + nf * 16 + l15] =
                            acc[f][nf][r] * g;
                    }
                }
    }
}

// ---------------------------------------------------------------------------
// Kernel 5: out[token] = OP[pair0] + OP[pair1]
// ---------------------------------------------------------------------------
__global__ void combine(const float* __restrict__ OP, const int* __restrict__ pair_row,
                        float* __restrict__ out) {
    int idx = blockIdx.x * blockDim.x + threadIdx.x;
    int token = idx >> 9;
    int q = idx & 511;
    int r0 = pair_row[token * 2 + 0];
    int r1 = pair_row[token * 2 + 1];
    float4 a = *(const float4*)(OP + (size_t)r0 * DIM + q * 4);
    float4 b = *(const float4*)(OP + (size_t)r1 * DIM + q * 4);
    float4 o;
    o.x = a.x + b.x; o.y = a.y + b.y; o.z = a.z + b.z; o.w = a.w + b.w;
    *(float4*)(out + (size_t)token * DIM + q * 4) = o;
}

// ---------------------------------------------------------------------------
extern "C" void kernel_launch(void* const* d_in, const int* in_sizes, int n_in,
                              void* d_out, int out_size, void* d_ws, size_t ws_size,
                              hipStream_t stream) {
    const float* x  = (const float*)d_in[0];
    const float* gw = (const float*)d_in[1];
    const float* w1 = (const float*)d_in[2];
    const float* w3 = (const float*)d_in[3];
    const float* w2 = (const float*)d_in[4];
    float* out = (float*)d_out;

    char* ws = (char*)d_ws;
    unsigned short* Hbuf = (unsigned short*)ws;                 // 8 MB bf16 [1024][4096]
    float* OP            = (float*)(ws + 8388608);              // 8 MB f32  [1024][2048]
    unsigned short* xbf  = (unsigned short*)(ws + 16777216);    // 2 MB bf16 [512][2048]
    char* meta           = ws + 18874368;
    int*   tok_expert = (int*)(meta);
    float* tok_gatew  = (float*)(meta + 4096);
    int*   counts     = (int*)(meta + 8192);
    int*   offsets    = (int*)(meta + 8224);
    int*   row_token  = (int*)(meta + 8256);
    float* row_gatew  = (float*)(meta + 12352);
    int*   pair_row   = (int*)(meta + 16448);

    gate_topk<<<TOK, 64, 0, stream>>>(x, gw, xbf, tok_expert, tok_gatew);
    build_lists<<<1, 512, 0, stream>>>(tok_expert, tok_gatew, counts, offsets,
                                       row_token, row_gatew, pair_row);
    ffn1<<<NE * 64, 512, 0, stream>>>(xbf, w1, w3, counts, offsets, row_token, Hbuf);
    ffn2<<<NE * 32, 512, 0, stream>>>(Hbuf, w2, counts, offsets, row_gatew, OP);
    combine<<<1024, 256, 0, stream>>>(OP, pair_row, out);
}